// Round 5
// baseline (239.819 us; speedup 1.0000x reference)
//
#include <hip/hip_runtime.h>
#include <math.h>

// OrbitalCofactorAntiequivarianceLayer fused kernel for MI355X (gfx950).
// B=4096, NSPIN=2, NPS=16, D=256, NION=8, DIM=3.
// 2048 blocks x 256 threads; block < 1024 -> s=0, else s=1; each of the
// 4 waves in a block owns pair b = (blk&1023)*4 + wave.
//
// Accuracy note: harness threshold is 2% of max|ref| (9.8e-12 vs 4.9e-10).
// fp32 LU w/ partial pivoting gives |cof| rel err ~ n^2*eps ~ 3e-5 -> ~1e-14
// absolute. f64 is unnecessary; Phase D is pure fp32 + 32-bit shuffles.

__global__ __launch_bounds__(256)
void cof_fused(const float* __restrict__ eq,    // (B,32,256)
               const float* __restrict__ rei,   // (B,32,8,3)
               const float* __restrict__ Wm,    // (2,256,16)
               const float* __restrict__ bb,    // (2,16)
               const float* __restrict__ edim,  // (2,8,16,3,3)
               const float* __restrict__ eion,  // (2,8,16)
               float* __restrict__ out)         // (B,2,16)
{
  __shared__ __align__(16) float Gl[8 * 6 * 16];   // Gram coeffs, SoA [i][c6][o]
  __shared__ __align__(16) float Ml[4 * 328];      // per-pair M (16x16, row stride 20)

  const int tid   = threadIdx.x;
  const int lane  = tid & 63;
  const int wv    = tid >> 6;
  const int blk   = blockIdx.x;
  const int sp    = blk >> 10;           // spin index
  const int bbase = (blk & 1023) * 4;

  // ---- Gram precompute: G = A^T A per (i,o), cross terms pre-doubled ----
  if (tid < 128) {
    const int i = tid >> 4, o = tid & 15;
    const float* A = edim + (((size_t)sp * 8 + i) * 16 + o) * 9;
    const float a0=A[0],a1=A[1],a2=A[2],a3=A[3],a4=A[4],a5=A[5],a6=A[6],a7=A[7],a8=A[8];
    float* Gp = Gl + i * 96 + o;
    Gp[0]  = a0*a0 + a3*a3 + a6*a6;
    Gp[16] = a1*a1 + a4*a4 + a7*a7;
    Gp[32] = a2*a2 + a5*a5 + a8*a8;
    Gp[48] = 2.f*(a0*a1 + a3*a4 + a6*a7);
    Gp[64] = 2.f*(a0*a2 + a3*a5 + a6*a8);
    Gp[80] = 2.f*(a1*a2 + a4*a5 + a7*a8);
  }
  __syncthreads();

  const int bidx = bbase + wv;
  const int cch  = lane >> 4;        // K-chunk (4 x 64 d)
  const int nb   = (lane >> 2) & 3;  // row-tile
  const int ob   = lane & 3;         // col-tile

  const float* xb = eq + ((size_t)bidx * 32 + sp * 16) * 256;
  const float* wb = Wm + (size_t)sp * 4096;

  // ---- Phase A: y = xs @ W, 4x4 register tile, global-direct loads ----
  float acc[4][4] = {{0.f,0.f,0.f,0.f},{0.f,0.f,0.f,0.f},
                     {0.f,0.f,0.f,0.f},{0.f,0.f,0.f,0.f}};
  #pragma unroll 2
  for (int q = 0; q < 16; ++q) {
    const int d0 = cch * 64 + q * 4;
    float xr[4][4], wr[4][4];
    #pragma unroll
    for (int r = 0; r < 4; ++r) {
      float4 t = *(const float4*)(xb + (4 * nb + r) * 256 + d0);
      xr[r][0]=t.x; xr[r][1]=t.y; xr[r][2]=t.z; xr[r][3]=t.w;
    }
    #pragma unroll
    for (int j = 0; j < 4; ++j) {
      float4 t = *(const float4*)(wb + (d0 + j) * 16 + 4 * ob);
      wr[j][0]=t.x; wr[j][1]=t.y; wr[j][2]=t.z; wr[j][3]=t.w;
    }
    #pragma unroll
    for (int r = 0; r < 4; ++r)
      #pragma unroll
      for (int j = 0; j < 4; ++j)
        #pragma unroll
        for (int c2 = 0; c2 < 4; ++c2)
          acc[r][c2] = fmaf(xr[r][j], wr[j][c2], acc[r][c2]);
  }

  // reduce over K-chunks (lane bits 4-5)
  #pragma unroll
  for (int r = 0; r < 4; ++r)
    #pragma unroll
    for (int c2 = 0; c2 < 4; ++c2) {
      float v = acc[r][c2];
      v += __shfl_xor(v, 16);
      v += __shfl_xor(v, 32);
      acc[r][c2] = v;
    }

  {
    float4 bv = *(const float4*)(bb + sp * 16 + 4 * ob);
    if (lane < 16) {
      #pragma unroll
      for (int r = 0; r < 4; ++r) {
        float4 v = make_float4(acc[r][0] + bv.x, acc[r][1] + bv.y,
                               acc[r][2] + bv.z, acc[r][3] + bv.w);
        *(float4*)(Ml + wv * 328 + (4 * nb + r) * 20 + 4 * ob) = v;
      }
    }
  }
  __syncthreads();

  // ---- Phase C: envelope; M = y * env (in place) ----
  {
    const int n = lane >> 2;           // row 0..15, cols 4*ob..4*ob+3
    const float* rp = rei + ((size_t)bidx * 32 + sp * 16 + n) * 24;
    float rv[24];
    #pragma unroll
    for (int t4 = 0; t4 < 6; ++t4) {
      float4 t = *(const float4*)(rp + t4 * 4);
      rv[t4*4+0]=t.x; rv[t4*4+1]=t.y; rv[t4*4+2]=t.z; rv[t4*4+3]=t.w;
    }
    float4 env = make_float4(0.f, 0.f, 0.f, 0.f);
    #pragma unroll
    for (int i = 0; i < 8; ++i) {
      const float r0 = rv[i*3], r1 = rv[i*3+1], r2 = rv[i*3+2];
      const float rr0 = r0*r0, rr1 = r1*r1, rr2 = r2*r2;
      const float rr3 = r0*r1, rr4 = r0*r2, rr5 = r1*r2;
      const float* Gp = Gl + i * 96 + 4 * ob;
      const float4 q00 = *(const float4*)(Gp);
      const float4 q11 = *(const float4*)(Gp + 16);
      const float4 q22 = *(const float4*)(Gp + 32);
      const float4 q01 = *(const float4*)(Gp + 48);
      const float4 q02 = *(const float4*)(Gp + 64);
      const float4 q12 = *(const float4*)(Gp + 80);
      const float4 io  = *(const float4*)(eion + ((size_t)sp * 8 + i) * 16 + 4 * ob);
#define ENVC(c) { float n2 = q00.c*rr0 + q11.c*rr1 + q22.c*rr2 \
                           + q01.c*rr3 + q02.c*rr4 + q12.c*rr5; \
                  n2 = fmaxf(n2, 0.f); \
                  env.c += expf(-sqrtf(n2)) * io.c; }
      ENVC(x) ENVC(y) ENVC(z) ENVC(w)
#undef ENVC
    }
    float* mp = Ml + wv * 328 + n * 20 + 4 * ob;
    float4 y = *(const float4*)mp;
    *(float4*)mp = make_float4(y.x * env.x, y.y * env.y, y.z * env.z, y.w * env.w);
  }
  __syncthreads();

  // ---- Phase D: cofactors. wave 0 does 4 matrices (16 lanes each).
  // A = M^T, fp32 LU with virtual partial pivoting; cof[i] = M[i,0]*det*x[i],
  // x = A^{-1} e0 (= row 0 of M^{-1}).
  if (wv == 0) {
    const int g  = lane >> 4;        // which pair in block
    const int r  = lane & 15;        // my row of A (= column r of M)
    const int gb = lane & 48;        // group base for shuffles
    const float* mg = Ml + g * 328;
    float a[16];
    #pragma unroll
    for (int c = 0; c < 16; ++c) a[c] = mg[c * 20 + r];

    float det = 1.0f;
    int sign = 0;
    unsigned retired = 0;
    int piv[16];
    int srr = 0;
    float accf = (r == 0) ? 1.0f : 0.0f;  // forward rhs (P e0 component for my row)
    float acc2 = 0.0f;                    // z captured at my retirement

    #pragma unroll
    for (int k = 0; k < 16; ++k) {
      const bool act = ((retired >> r) & 1u) == 0u;
      const float av = act ? fabsf(a[k]) : 0.0f;
      unsigned pk = (__float_as_uint(av) & 0xFFFFFFF0u) | (unsigned)r;
      #pragma unroll
      for (int m = 1; m <= 8; m <<= 1) {
        unsigned o2 = __shfl_xor(pk, m);
        pk = (pk > o2) ? pk : o2;
      }
      const int p = (int)(pk & 15u);
      piv[k] = p;
      float pv = __shfl(a[k], gb | p);
      if (fabsf(pv) < 1e-30f) pv = (pv < 0.0f) ? -1e-30f : 1e-30f;
      det *= pv;
      retired |= (1u << p);
      sign ^= (int)(__popc((~retired) & ((1u << p) - 1u)) & 1u);
      if (r == p) srr = k;
      const bool upd = act && (r != p);
      float m2 = 0.0f;
      if (upd) { m2 = a[k] / pv; a[k] = m2; }
      #pragma unroll
      for (int c = k + 1; c < 16; ++c) {
        float bcv = __shfl(a[c], gb | p);
        if (upd) a[c] = fmaf(-m2, bcv, a[c]);
      }
      // fused forward solve L z = P e0
      float zk = __shfl(accf, gb | p);
      if (r == p) acc2 = zk;
      if (upd) accf = fmaf(-m2, zk, accf);
    }
    if (sign) det = -det;

    // backward solve U x = z
    float myx = 0.0f;
    #pragma unroll
    for (int j = 15; j >= 0; --j) {
      float t = acc2 / a[j];                   // valid on pivot lane of step j
      float xj = __shfl(t, gb | piv[j]);
      if (srr < j) acc2 = fmaf(-a[j], xj, acc2);
      if (r == j) myx = xj;
    }

    const float mi0 = mg[r * 20];              // M[r][0]
    const float cof = mi0 * det * myx;
    out[((size_t)(bbase + g) * 2 + sp) * 16 + r] = cof;
  }
}

extern "C" void kernel_launch(void* const* d_in, const int* in_sizes, int n_in,
                              void* d_out, int out_size, void* d_ws, size_t ws_size,
                              hipStream_t stream) {
  (void)in_sizes; (void)n_in; (void)out_size; (void)d_ws; (void)ws_size;
  const float* eq   = (const float*)d_in[0];
  const float* rei  = (const float*)d_in[1];
  const float* Wm   = (const float*)d_in[2];
  const float* bb   = (const float*)d_in[3];
  const float* edim = (const float*)d_in[4];
  const float* eion = (const float*)d_in[5];
  float* out = (float*)d_out;
  hipLaunchKernelGGL(cof_fused, dim3(2048), dim3(256), 0, stream,
                     eq, rei, Wm, bb, edim, eion, out);
}

// Round 6
// 230.334 us; speedup vs baseline: 1.0412x; 1.0412x over previous
//
#include <hip/hip_runtime.h>
#include <math.h>

// OrbitalCofactorAntiequivarianceLayer fused kernel for MI355X (gfx950).
// B=4096, NSPIN=2, NPS=16, D=256, NION=8, DIM=3.
// 2048 blocks x 256 threads; block < 1024 -> s=0, else s=1; each of the
// 4 waves in a block owns pair b = (blk&1023)*4 + wave.
//
// R5 -> R6: Phase A x-loads were 16B-per-64B-line scattered (1.8 TB/s, 22%
// peak). Now: coalesced global->reg->LDS staging in two 8KB halves per pair
// (software-pipelined), XOR bank swizzle (2-way = free), interleaved K-chunk
// fragment mapping, __expf. LDS 35KB/block -> 4 blocks/CU.

__global__ __launch_bounds__(256)
void cof_fused(const float* __restrict__ eq,    // (B,32,256)
               const float* __restrict__ rei,   // (B,32,8,3)
               const float* __restrict__ Wm,    // (2,256,16)
               const float* __restrict__ bb,    // (2,16)
               const float* __restrict__ edim,  // (2,8,16,3,3)
               const float* __restrict__ eion,  // (2,8,16)
               float* __restrict__ out)         // (B,2,16)
{
  __shared__ __align__(16) float Gl[8 * 6 * 16];   // Gram coeffs, SoA [i][c6][o]
  __shared__ __align__(16) float Xl[4 * 2048];     // per-wave x half-tile (16x128),
                                                   // later overlaid by M (16x16, stride 20)

  const int tid   = threadIdx.x;
  const int lane  = tid & 63;
  const int wv    = tid >> 6;
  const int blk   = blockIdx.x;
  const int sp    = blk >> 10;           // spin index
  const int bbase = (blk & 1023) * 4;

  // ---- Gram precompute: G = A^T A per (i,o), cross terms pre-doubled ----
  if (tid < 128) {
    const int i = tid >> 4, o = tid & 15;
    const float* A = edim + (((size_t)sp * 8 + i) * 16 + o) * 9;
    const float a0=A[0],a1=A[1],a2=A[2],a3=A[3],a4=A[4],a5=A[5],a6=A[6],a7=A[7],a8=A[8];
    float* Gp = Gl + i * 96 + o;
    Gp[0]  = a0*a0 + a3*a3 + a6*a6;
    Gp[16] = a1*a1 + a4*a4 + a7*a7;
    Gp[32] = a2*a2 + a5*a5 + a8*a8;
    Gp[48] = 2.f*(a0*a1 + a3*a4 + a6*a7);
    Gp[64] = 2.f*(a0*a2 + a3*a5 + a6*a8);
    Gp[80] = 2.f*(a1*a2 + a4*a5 + a7*a8);
  }
  __syncthreads();

  const int bidx = bbase + wv;
  const int cch  = lane >> 4;        // K-chunk within a 16-float group
  const int nb   = (lane >> 2) & 3;  // row-tile
  const int ob   = lane & 3;         // col-tile

  const float* xb = eq + ((size_t)bidx * 32 + sp * 16) * 256;
  const float* wb = Wm + (size_t)sp * 4096;
  float* xw = Xl + wv * 2048;

  const int srow = 2 * 0 + (lane >> 5);      // staging row parity base
  const int schk = lane & 31;                // staging chunk within half-row

  float acc[4][4] = {{0.f,0.f,0.f,0.f},{0.f,0.f,0.f,0.f},
                     {0.f,0.f,0.f,0.f},{0.f,0.f,0.f,0.f}};

  // ---- Phase A: y = xs @ W. Stage x half (16 rows x 128 d) into LDS
  // coalesced, XOR-swizzled; software-pipeline the two halves. ----
  float4 st[8];
  // load half 0 (coalesced: 2x512B contiguous per instr)
  #pragma unroll
  for (int t = 0; t < 8; ++t)
    st[t] = *(const float4*)(xb + (2 * t + (lane >> 5)) * 256 + schk * 4);
  // write half 0 to LDS (chunk k stored at k ^ (row&7))
  #pragma unroll
  for (int t = 0; t < 8; ++t) {
    const int row = 2 * t + (lane >> 5);
    *(float4*)(xw + row * 128 + (schk ^ (row & 7)) * 4) = st[t];
  }
  // prefetch half 1 into registers
  float4 st2[8];
  #pragma unroll
  for (int t = 0; t < 8; ++t)
    st2[t] = *(const float4*)(xb + (2 * t + (lane >> 5)) * 256 + 128 + schk * 4);

  // compute half 0
  #pragma unroll 2
  for (int q = 0; q < 8; ++q) {
    const int d0 = q * 16 + cch * 4;         // global d (half 0)
    float xr[4][4], wr[4][4];
    #pragma unroll
    for (int r = 0; r < 4; ++r) {
      const int n = 4 * nb + r;
      float4 t = *(const float4*)(xw + n * 128 + ((q * 4 + cch) ^ (n & 7)) * 4);
      xr[r][0]=t.x; xr[r][1]=t.y; xr[r][2]=t.z; xr[r][3]=t.w;
    }
    #pragma unroll
    for (int j = 0; j < 4; ++j) {
      float4 t = *(const float4*)(wb + (d0 + j) * 16 + 4 * ob);
      wr[j][0]=t.x; wr[j][1]=t.y; wr[j][2]=t.z; wr[j][3]=t.w;
    }
    #pragma unroll
    for (int r = 0; r < 4; ++r)
      #pragma unroll
      for (int j = 0; j < 4; ++j)
        #pragma unroll
        for (int c2 = 0; c2 < 4; ++c2)
          acc[r][c2] = fmaf(xr[r][j], wr[j][c2], acc[r][c2]);
  }

  // write half 1 to LDS (half-0 reads architecturally complete: data consumed)
  #pragma unroll
  for (int t = 0; t < 8; ++t) {
    const int row = 2 * t + (lane >> 5);
    *(float4*)(xw + row * 128 + (schk ^ (row & 7)) * 4) = st2[t];
  }
  // compute half 1
  #pragma unroll 2
  for (int q = 0; q < 8; ++q) {
    const int d0 = 128 + q * 16 + cch * 4;   // global d (half 1)
    float xr[4][4], wr[4][4];
    #pragma unroll
    for (int r = 0; r < 4; ++r) {
      const int n = 4 * nb + r;
      float4 t = *(const float4*)(xw + n * 128 + ((q * 4 + cch) ^ (n & 7)) * 4);
      xr[r][0]=t.x; xr[r][1]=t.y; xr[r][2]=t.z; xr[r][3]=t.w;
    }
    #pragma unroll
    for (int j = 0; j < 4; ++j) {
      float4 t = *(const float4*)(wb + (d0 + j) * 16 + 4 * ob);
      wr[j][0]=t.x; wr[j][1]=t.y; wr[j][2]=t.z; wr[j][3]=t.w;
    }
    #pragma unroll
    for (int r = 0; r < 4; ++r)
      #pragma unroll
      for (int j = 0; j < 4; ++j)
        #pragma unroll
        for (int c2 = 0; c2 < 4; ++c2)
          acc[r][c2] = fmaf(xr[r][j], wr[j][c2], acc[r][c2]);
  }

  // reduce over K-chunks (lane bits 4-5)
  #pragma unroll
  for (int r = 0; r < 4; ++r)
    #pragma unroll
    for (int c2 = 0; c2 < 4; ++c2) {
      float v = acc[r][c2];
      v += __shfl_xor(v, 16);
      v += __shfl_xor(v, 32);
      acc[r][c2] = v;
    }

  // M overlays this wave's x buffer (x fully consumed by this wave).
  float* Mw = xw;   // 16 rows, stride 20 floats
  {
    float4 bv = *(const float4*)(bb + sp * 16 + 4 * ob);
    if (lane < 16) {
      #pragma unroll
      for (int r = 0; r < 4; ++r) {
        float4 v = make_float4(acc[r][0] + bv.x, acc[r][1] + bv.y,
                               acc[r][2] + bv.z, acc[r][3] + bv.w);
        *(float4*)(Mw + (4 * nb + r) * 20 + 4 * ob) = v;
      }
    }
  }

  // ---- Phase C: envelope; M = y * env (in place, own-wave region) ----
  {
    const int n = lane >> 2;           // row 0..15, cols 4*ob..4*ob+3
    const float* rp = rei + ((size_t)bidx * 32 + sp * 16 + n) * 24;
    float rv[24];
    #pragma unroll
    for (int t4 = 0; t4 < 6; ++t4) {
      float4 t = *(const float4*)(rp + t4 * 4);
      rv[t4*4+0]=t.x; rv[t4*4+1]=t.y; rv[t4*4+2]=t.z; rv[t4*4+3]=t.w;
    }
    float4 env = make_float4(0.f, 0.f, 0.f, 0.f);
    #pragma unroll
    for (int i = 0; i < 8; ++i) {
      const float r0 = rv[i*3], r1 = rv[i*3+1], r2 = rv[i*3+2];
      const float rr0 = r0*r0, rr1 = r1*r1, rr2 = r2*r2;
      const float rr3 = r0*r1, rr4 = r0*r2, rr5 = r1*r2;
      const float* Gp = Gl + i * 96 + 4 * ob;
      const float4 q00 = *(const float4*)(Gp);
      const float4 q11 = *(const float4*)(Gp + 16);
      const float4 q22 = *(const float4*)(Gp + 32);
      const float4 q01 = *(const float4*)(Gp + 48);
      const float4 q02 = *(const float4*)(Gp + 64);
      const float4 q12 = *(const float4*)(Gp + 80);
      const float4 io  = *(const float4*)(eion + ((size_t)sp * 8 + i) * 16 + 4 * ob);
#define ENVC(c) { float n2 = q00.c*rr0 + q11.c*rr1 + q22.c*rr2 \
                           + q01.c*rr3 + q02.c*rr4 + q12.c*rr5; \
                  n2 = fmaxf(n2, 0.f); \
                  env.c += __expf(-sqrtf(n2)) * io.c; }
      ENVC(x) ENVC(y) ENVC(z) ENVC(w)
#undef ENVC
    }
    float* mp = Mw + n * 20 + 4 * ob;
    float4 y = *(const float4*)mp;
    *(float4*)mp = make_float4(y.x * env.x, y.y * env.y, y.z * env.z, y.w * env.w);
  }
  __syncthreads();

  // ---- Phase D: cofactors. wave 0 does 4 matrices (16 lanes each).
  // A = M^T, fp32 LU with virtual partial pivoting; cof[i] = M[i,0]*det*x[i],
  // x = A^{-1} e0 (= row 0 of M^{-1}).
  if (wv == 0) {
    const int g  = lane >> 4;        // which pair in block
    const int r  = lane & 15;        // my row of A (= column r of M)
    const int gb = lane & 48;        // group base for shuffles
    const float* mg = Xl + g * 2048; // pair g's M
    float a[16];
    #pragma unroll
    for (int c = 0; c < 16; ++c) a[c] = mg[c * 20 + r];

    float det = 1.0f;
    int sign = 0;
    unsigned retired = 0;
    int piv[16];
    int srr = 0;
    float accf = (r == 0) ? 1.0f : 0.0f;  // forward rhs (P e0 component)
    float acc2 = 0.0f;                    // z captured at my retirement

    #pragma unroll
    for (int k = 0; k < 16; ++k) {
      const bool act = ((retired >> r) & 1u) == 0u;
      const float av = act ? fabsf(a[k]) : 0.0f;
      unsigned pk = (__float_as_uint(av) & 0xFFFFFFF0u) | (unsigned)r;
      #pragma unroll
      for (int m = 1; m <= 8; m <<= 1) {
        unsigned o2 = __shfl_xor(pk, m);
        pk = (pk > o2) ? pk : o2;
      }
      const int p = (int)(pk & 15u);
      piv[k] = p;
      float pv = __shfl(a[k], gb | p);
      if (fabsf(pv) < 1e-30f) pv = (pv < 0.0f) ? -1e-30f : 1e-30f;
      det *= pv;
      retired |= (1u << p);
      sign ^= (int)(__popc((~retired) & ((1u << p) - 1u)) & 1u);
      if (r == p) srr = k;
      const bool upd = act && (r != p);
      float m2 = 0.0f;
      if (upd) { m2 = a[k] / pv; a[k] = m2; }
      #pragma unroll
      for (int c = k + 1; c < 16; ++c) {
        float bcv = __shfl(a[c], gb | p);
        if (upd) a[c] = fmaf(-m2, bcv, a[c]);
      }
      // fused forward solve L z = P e0
      float zk = __shfl(accf, gb | p);
      if (r == p) acc2 = zk;
      if (upd) accf = fmaf(-m2, zk, accf);
    }
    if (sign) det = -det;

    // backward solve U x = z
    float myx = 0.0f;
    #pragma unroll
    for (int j = 15; j >= 0; --j) {
      float t = acc2 / a[j];                   // valid on pivot lane of step j
      float xj = __shfl(t, gb | piv[j]);
      if (srr < j) acc2 = fmaf(-a[j], xj, acc2);
      if (r == j) myx = xj;
    }

    const float mi0 = mg[r * 20];              // M[r][0]
    const float cof = mi0 * det * myx;
    out[((size_t)(bbase + g) * 2 + sp) * 16 + r] = cof;
  }
}

extern "C" void kernel_launch(void* const* d_in, const int* in_sizes, int n_in,
                              void* d_out, int out_size, void* d_ws, size_t ws_size,
                              hipStream_t stream) {
  (void)in_sizes; (void)n_in; (void)out_size; (void)d_ws; (void)ws_size;
  const float* eq   = (const float*)d_in[0];
  const float* rei  = (const float*)d_in[1];
  const float* Wm   = (const float*)d_in[2];
  const float* bb   = (const float*)d_in[3];
  const float* edim = (const float*)d_in[4];
  const float* eion = (const float*)d_in[5];
  float* out = (float*)d_out;
  hipLaunchKernelGGL(cof_fused, dim3(2048), dim3(256), 0, stream,
                     eq, rei, Wm, bb, edim, eion, out);
}